// Round 3
// baseline (297.265 us; speedup 1.0000x reference)
//
#include <hip/hip_runtime.h>
#include <cstddef>

// Problem constants
#define BB 8
#define CC 64
#define OO 64
#define HH 256
#define WW 256
#define MODES 16

// Workspace layout (float offsets) — same as round 2; xbar_h slot now unused.
#define WS_XBAR   0
#define WS_FTRE   262144
#define WS_FTIM   278528
#define WS_BOXRE  294912
#define WS_BOXIM  311296
#define WS_G      327680

typedef __attribute__((ext_vector_type(8)))  short short8v;
typedef __attribute__((ext_vector_type(4)))  int   int4v;
typedef __attribute__((ext_vector_type(16))) float f32x16;

// HW packed f32->bf16 (RNE): lo = bf16(a), hi = bf16(b)
__device__ __forceinline__ unsigned pack_bf16(float a, float b) {
    unsigned r;
    asm("v_cvt_pk_bf16_f32 %0, %1, %2" : "=v"(r) : "v"(a), "v"(b));
    return r;
}

// ---------------------------------------------------------------------------
// K1: grid = B*C*4. Block j of slice bc handles rows [j*64, j*64+64):
//  - row means -> xbw[bc][h] (final)
//  - column partial sums over its 64 rows -> partial[bc*4+j][w] (in d_out!)
__global__ void k_means(const float* __restrict__ x,
                        float* __restrict__ xbw,       // [B*C][256]
                        float* __restrict__ partial) { // [B*C*4][256] (d_out scratch)
    const int blk = blockIdx.x;                  // bc*4 + j
    const int bc  = blk >> 2;
    const int j   = blk & 3;
    const int t   = threadIdx.x;
    const int wave = t >> 6;
    const int lane = t & 63;
    const float* xs = x + (size_t)bc * (HH * WW);

    __shared__ float colsum[4][WW];

    float c0 = 0.f, c1 = 0.f, c2 = 0.f, c3 = 0.f;
    const int h0 = j * 64 + wave * 16;
    for (int r = 0; r < 16; ++r) {
        const int h = h0 + r;
        const float4 v = *reinterpret_cast<const float4*>(xs + (size_t)h * WW + lane * 4);
        c0 += v.x; c1 += v.y; c2 += v.z; c3 += v.w;
        float rs = (v.x + v.y) + (v.z + v.w);
        #pragma unroll
        for (int off = 32; off > 0; off >>= 1) rs += __shfl_xor(rs, off, 64);
        if (lane == 0) xbw[bc * HH + h] = rs * (1.0f / WW);
    }
    colsum[wave][lane * 4 + 0] = c0;
    colsum[wave][lane * 4 + 1] = c1;
    colsum[wave][lane * 4 + 2] = c2;
    colsum[wave][lane * 4 + 3] = c3;
    __syncthreads();
    partial[blk * WW + t] =
        (colsum[0][t] + colsum[1][t]) + (colsum[2][t] + colsum[3][t]);
}

// ---------------------------------------------------------------------------
// K2a: 16-mode ortho DFT. blk<512: row-mean vectors (xbw). blk>=512: column
// means assembled from the 4 partials (divide by H here).
__global__ void k_dft(const float* __restrict__ xbw,
                      const float* __restrict__ partial,
                      float* __restrict__ ftre,        // [1024][16]
                      float* __restrict__ ftim) {
    const int blk = blockIdx.x;
    const int t = threadIdx.x;
    __shared__ float vs[256];
    if (blk < 512) {
        vs[t] = xbw[(size_t)blk * 256 + t];
    } else {
        const int bc = blk - 512;
        vs[t] = ((partial[(bc * 4 + 0) * 256 + t] + partial[(bc * 4 + 1) * 256 + t]) +
                 (partial[(bc * 4 + 2) * 256 + t] + partial[(bc * 4 + 3) * 256 + t])) *
                (1.0f / HH);
    }
    __syncthreads();

    const int k = t >> 4;
    const int j = t & 15;
    float sre = 0.f, sim = 0.f;
    const float wk = 6.2831853071795864769f * (float)k / 256.0f;
    #pragma unroll
    for (int i = 0; i < 16; ++i) {
        const int h = j * 16 + i;
        float s, c;
        sincosf(wk * (float)h, &s, &c);
        sre += vs[h] * c;
        sim -= vs[h] * s;
    }
    #pragma unroll
    for (int m = 1; m < 16; m <<= 1) {
        sre += __shfl_xor(sre, m, 64);
        sim += __shfl_xor(sim, m, 64);
    }
    if (j == 0) {
        ftre[blk * MODES + k] = sre * (1.0f / 16.0f);
        ftim[blk * MODES + k] = sim * (1.0f / 16.0f);
    }
}

// ---------------------------------------------------------------------------
// K2b: channel mix in mode space.
__global__ void k_modemix(const float* __restrict__ ftre,
                          const float* __restrict__ ftim,
                          const float* __restrict__ wxr, const float* __restrict__ wxi,
                          const float* __restrict__ wyr, const float* __restrict__ wyi,
                          float* __restrict__ boxre, float* __restrict__ boxim) {
    const int blk = blockIdx.x;      // 0..15 : br = blk>>3, b = blk&7
    const int br  = blk >> 3;
    const int t   = threadIdx.x;

    const float* wr = br ? wyr : wxr;
    const float* wi = br ? wyi : wxi;

    __shared__ float fr[CC * MODES];
    __shared__ float fi[CC * MODES];
    #pragma unroll
    for (int i = 0; i < 4; ++i) {
        fr[t + i * 256] = ftre[blk * (CC * MODES) + t + i * 256];
        fi[t + i * 256] = ftim[blk * (CC * MODES) + t + i * 256];
    }
    __syncthreads();

    const int k  = t & 15;
    const int ob = t >> 4;
    #pragma unroll
    for (int p = 0; p < 4; ++p) {
        const int o = ob + p * 16;
        float are = 0.f, aim = 0.f;
        for (int c = 0; c < CC; ++c) {
            const float frv = fr[c * MODES + k];
            const float fiv = fi[c * MODES + k];
            const float wrv = wr[(c * OO + o) * MODES + k];
            const float wiv = wi[(c * OO + o) * MODES + k];
            are += frv * wrv - fiv * wiv;
            aim += frv * wiv + fiv * wrv;
        }
        boxre[blk * (OO * MODES) + o * MODES + k] = are;
        boxim[blk * (OO * MODES) + o * MODES + k] = aim;
    }
}

// ---------------------------------------------------------------------------
// K2c: inverse synthesis; mix_b folded into gx (br==0).
__global__ void k_synth(const float* __restrict__ boxre,
                        const float* __restrict__ boxim,
                        const float* __restrict__ mb,
                        float* __restrict__ g) {
    const int blk = blockIdx.x;      // (br*B+b)*64 + o
    const int t   = threadIdx.x;
    __shared__ float bre[MODES], bim[MODES];
    if (t < MODES)        bre[t] = boxre[(blk >> 6) * (OO * MODES) + (blk & 63) * MODES + t];
    else if (t < 2*MODES) bim[t - MODES] = boxim[(blk >> 6) * (OO * MODES) + (blk & 63) * MODES + (t - MODES)];
    __syncthreads();

    float acc = bre[0];
    const float wt = 6.2831853071795864769f * (float)t / 256.0f;
    #pragma unroll
    for (int k = 1; k < MODES; ++k) {
        float s, c;
        sincosf(wt * (float)k, &s, &c);
        acc += 2.0f * (bre[k] * c - bim[k] * s);
    }
    float v = acc * (1.0f / 16.0f);
    if (blk < BB * OO) v += mb[blk & 63];
    g[(size_t)blk * 256 + t] = v;
}

// ---------------------------------------------------------------------------
// K3: MFMA epilogue GEMM, ot-merged, pure bf16 single-term.
// out[b,o,h,w] = sum_c mw[o,c] x[b,c,h,w] + gx'[b,o,h] + gy[b,o,w]
// grid = B * 128 strips of 512 px; 4 waves; wave does 4 x 32-pixel tiles,
// computing ALL 64 o per tile (two 32x32 acc tiles share one x load/convert).
__global__ void __launch_bounds__(256, 4) k_final_mfma(
        const float* __restrict__ x,
        const float* __restrict__ mw,   // [O][C]
        const float* __restrict__ g,    // [2][B][O][256]
        float* __restrict__ out) {
    const int tid  = threadIdx.x;
    const int lane = tid & 63;
    const int wv   = tid >> 6;
    const int blk  = blockIdx.x;
    const int strip = blk & 127;
    const int b     = blk >> 7;
    const int nlo   = lane & 31;
    const int half  = lane >> 5;

    const float* gx = g + (size_t)(b * OO) * 256;
    const float* gy = g + (size_t)BB * OO * 256 + (size_t)(b * OO) * 256;

    // A fragments (weights) for both o-tiles, bf16, loaded once.
    short8v wf[2][4];
    #pragma unroll
    for (int ot = 0; ot < 2; ++ot) {
        const int o = ot * 32 + nlo;
        const float* wrow = mw + o * CC + 8 * half;
        #pragma unroll
        for (int kb = 0; kb < 4; ++kb) {
            int4v wi;
            #pragma unroll
            for (int p = 0; p < 4; ++p)
                wi[p] = (int)pack_bf16(wrow[kb * 16 + 2 * p], wrow[kb * 16 + 2 * p + 1]);
            wf[ot][kb] = __builtin_bit_cast(short8v, wi);
        }
    }

    const float* xb = x + (size_t)b * CC * (HH * WW);
    float*       ob = out + (size_t)b * OO * (HH * WW);

    for (int it = 0; it < 4; ++it) {
        const int p0 = strip * 512 + it * 128 + wv * 32;
        const int h  = p0 >> 8;
        const int w0 = p0 & 255;

        // gather B: x[c][p0+nlo], c = kb*16 + 8*half + i
        float xv[32];
        #pragma unroll
        for (int kb = 0; kb < 4; ++kb)
            #pragma unroll
            for (int i = 0; i < 8; ++i) {
                const int c = kb * 16 + 8 * half + i;
                xv[kb * 8 + i] = xb[(size_t)c * (HH * WW) + p0 + nlo];
            }

        short8v xh[4];
        #pragma unroll
        for (int kb = 0; kb < 4; ++kb) {
            int4v xi;
            #pragma unroll
            for (int p = 0; p < 4; ++p)
                xi[p] = (int)pack_bf16(xv[kb * 8 + 2 * p], xv[kb * 8 + 2 * p + 1]);
            xh[kb] = __builtin_bit_cast(short8v, xi);
        }

        f32x16 acc0, acc1;
        #pragma unroll
        for (int i = 0; i < 16; ++i) { acc0[i] = 0.f; acc1[i] = 0.f; }

        #pragma unroll
        for (int kb = 0; kb < 4; ++kb) {
            acc0 = __builtin_amdgcn_mfma_f32_32x32x16_bf16(wf[0][kb], xh[kb], acc0, 0, 0, 0);
            acc1 = __builtin_amdgcn_mfma_f32_32x32x16_bf16(wf[1][kb], xh[kb], acc1, 0, 0, 0);
        }

        // epilogue: row(o_local) = (r&3) + 8*(r>>2) + 4*half, col = nlo
        #pragma unroll
        for (int r = 0; r < 16; ++r) {
            const int ol = (r & 3) + 8 * (r >> 2) + 4 * half;
            {
                const int o = ol;
                const float v = acc0[r] + gx[o * 256 + h] + gy[o * 256 + w0 + nlo];
                ob[(size_t)o * (HH * WW) + p0 + nlo] = v;
            }
            {
                const int o = 32 + ol;
                const float v = acc1[r] + gx[o * 256 + h] + gy[o * 256 + w0 + nlo];
                ob[(size_t)o * (HH * WW) + p0 + nlo] = v;
            }
        }
    }
}

// ---------------------------------------------------------------------------
extern "C" void kernel_launch(void* const* d_in, const int* in_sizes, int n_in,
                              void* d_out, int out_size, void* d_ws, size_t ws_size,
                              hipStream_t stream) {
    const float* x    = (const float*)d_in[0];
    const float* wxr  = (const float*)d_in[1];
    const float* wxi  = (const float*)d_in[2];
    const float* wyr  = (const float*)d_in[3];
    const float* wyi  = (const float*)d_in[4];
    const float* mixw = (const float*)d_in[5];
    const float* mixb = (const float*)d_in[6];
    float* out = (float*)d_out;
    float* ws  = (float*)d_ws;

    float* xbw   = ws + WS_XBAR;
    float* ftre  = ws + WS_FTRE;
    float* ftim  = ws + WS_FTIM;
    float* boxre = ws + WS_BOXRE;
    float* boxim = ws + WS_BOXIM;
    float* g     = ws + WS_G;
    float* partial = out;    // d_out as scratch: dead until k_final overwrites

    k_means<<<BB * CC * 4, 256, 0, stream>>>(x, xbw, partial);
    k_dft<<<2 * BB * CC, 256, 0, stream>>>(xbw, partial, ftre, ftim);
    k_modemix<<<2 * BB, 256, 0, stream>>>(ftre, ftim, wxr, wxi, wyr, wyi, boxre, boxim);
    k_synth<<<2 * BB * OO, 256, 0, stream>>>(boxre, boxim, mixb, g);
    k_final_mfma<<<BB * 128, 256, 0, stream>>>(x, mixw, g, out);
}

// Round 4
// 211.372 us; speedup vs baseline: 1.4064x; 1.4064x over previous
//
#include <hip/hip_runtime.h>
#include <cstddef>

// Problem constants
#define BB 8
#define CC 64
#define OO 64
#define HH 256
#define WW 256
#define MODES 16

// Workspace layout (float offsets)
#define WS_XBAR   0
#define WS_FTRE   262144
#define WS_FTIM   278528
#define WS_BOXRE  294912
#define WS_BOXIM  311296
#define WS_G      327680

typedef __attribute__((ext_vector_type(8)))  short short8v;
typedef __attribute__((ext_vector_type(4)))  int   int4v;
typedef __attribute__((ext_vector_type(16))) float f32x16;

// HW packed f32->bf16 (RNE): lo = bf16(a), hi = bf16(b)
__device__ __forceinline__ unsigned pack_bf16(float a, float b) {
    unsigned r;
    asm("v_cvt_pk_bf16_f32 %0, %1, %2" : "=v"(r) : "v"(a), "v"(b));
    return r;
}

// ---------------------------------------------------------------------------
// K1: grid = B*C*4. Block j of slice bc handles rows [j*64, j*64+64):
//  - row means -> xbw[bc][h] (final)
//  - column partial sums over its 64 rows -> partial[bc*4+j][w] (in d_out!)
__global__ void k_means(const float* __restrict__ x,
                        float* __restrict__ xbw,       // [B*C][256]
                        float* __restrict__ partial) { // [B*C*4][256] (d_out scratch)
    const int blk = blockIdx.x;                  // bc*4 + j
    const int bc  = blk >> 2;
    const int j   = blk & 3;
    const int t   = threadIdx.x;
    const int wave = t >> 6;
    const int lane = t & 63;
    const float* xs = x + (size_t)bc * (HH * WW);

    __shared__ float colsum[4][WW];

    float c0 = 0.f, c1 = 0.f, c2 = 0.f, c3 = 0.f;
    const int h0 = j * 64 + wave * 16;
    for (int r = 0; r < 16; ++r) {
        const int h = h0 + r;
        const float4 v = *reinterpret_cast<const float4*>(xs + (size_t)h * WW + lane * 4);
        c0 += v.x; c1 += v.y; c2 += v.z; c3 += v.w;
        float rs = (v.x + v.y) + (v.z + v.w);
        #pragma unroll
        for (int off = 32; off > 0; off >>= 1) rs += __shfl_xor(rs, off, 64);
        if (lane == 0) xbw[bc * HH + h] = rs * (1.0f / WW);
    }
    colsum[wave][lane * 4 + 0] = c0;
    colsum[wave][lane * 4 + 1] = c1;
    colsum[wave][lane * 4 + 2] = c2;
    colsum[wave][lane * 4 + 3] = c3;
    __syncthreads();
    partial[blk * WW + t] =
        (colsum[0][t] + colsum[1][t]) + (colsum[2][t] + colsum[3][t]);
}

// ---------------------------------------------------------------------------
// K2a: 16-mode ortho DFT. blk<512: row-mean vectors (xbw). blk>=512: column
// means assembled from the 4 partials (divide by H here).
__global__ void k_dft(const float* __restrict__ xbw,
                      const float* __restrict__ partial,
                      float* __restrict__ ftre,        // [1024][16]
                      float* __restrict__ ftim) {
    const int blk = blockIdx.x;
    const int t = threadIdx.x;
    __shared__ float vs[256];
    if (blk < 512) {
        vs[t] = xbw[(size_t)blk * 256 + t];
    } else {
        const int bc = blk - 512;
        vs[t] = ((partial[(bc * 4 + 0) * 256 + t] + partial[(bc * 4 + 1) * 256 + t]) +
                 (partial[(bc * 4 + 2) * 256 + t] + partial[(bc * 4 + 3) * 256 + t])) *
                (1.0f / HH);
    }
    __syncthreads();

    const int k = t >> 4;
    const int j = t & 15;
    float sre = 0.f, sim = 0.f;
    const float wk = 6.2831853071795864769f * (float)k / 256.0f;
    #pragma unroll
    for (int i = 0; i < 16; ++i) {
        const int h = j * 16 + i;
        float s, c;
        sincosf(wk * (float)h, &s, &c);
        sre += vs[h] * c;
        sim -= vs[h] * s;
    }
    #pragma unroll
    for (int m = 1; m < 16; m <<= 1) {
        sre += __shfl_xor(sre, m, 64);
        sim += __shfl_xor(sim, m, 64);
    }
    if (j == 0) {
        ftre[blk * MODES + k] = sre * (1.0f / 16.0f);
        ftim[blk * MODES + k] = sim * (1.0f / 16.0f);
    }
}

// ---------------------------------------------------------------------------
// K2b: channel mix in mode space.
__global__ void k_modemix(const float* __restrict__ ftre,
                          const float* __restrict__ ftim,
                          const float* __restrict__ wxr, const float* __restrict__ wxi,
                          const float* __restrict__ wyr, const float* __restrict__ wyi,
                          float* __restrict__ boxre, float* __restrict__ boxim) {
    const int blk = blockIdx.x;      // 0..15 : br = blk>>3, b = blk&7
    const int br  = blk >> 3;
    const int t   = threadIdx.x;

    const float* wr = br ? wyr : wxr;
    const float* wi = br ? wyi : wxi;

    __shared__ float fr[CC * MODES];
    __shared__ float fi[CC * MODES];
    #pragma unroll
    for (int i = 0; i < 4; ++i) {
        fr[t + i * 256] = ftre[blk * (CC * MODES) + t + i * 256];
        fi[t + i * 256] = ftim[blk * (CC * MODES) + t + i * 256];
    }
    __syncthreads();

    const int k  = t & 15;
    const int ob = t >> 4;
    #pragma unroll
    for (int p = 0; p < 4; ++p) {
        const int o = ob + p * 16;
        float are = 0.f, aim = 0.f;
        for (int c = 0; c < CC; ++c) {
            const float frv = fr[c * MODES + k];
            const float fiv = fi[c * MODES + k];
            const float wrv = wr[(c * OO + o) * MODES + k];
            const float wiv = wi[(c * OO + o) * MODES + k];
            are += frv * wrv - fiv * wiv;
            aim += frv * wiv + fiv * wrv;
        }
        boxre[blk * (OO * MODES) + o * MODES + k] = are;
        boxim[blk * (OO * MODES) + o * MODES + k] = aim;
    }
}

// ---------------------------------------------------------------------------
// K2c: inverse synthesis; mix_b folded into gx (br==0).
__global__ void k_synth(const float* __restrict__ boxre,
                        const float* __restrict__ boxim,
                        const float* __restrict__ mb,
                        float* __restrict__ g) {
    const int blk = blockIdx.x;      // (br*B+b)*64 + o
    const int t   = threadIdx.x;
    __shared__ float bre[MODES], bim[MODES];
    if (t < MODES)        bre[t] = boxre[(blk >> 6) * (OO * MODES) + (blk & 63) * MODES + t];
    else if (t < 2*MODES) bim[t - MODES] = boxim[(blk >> 6) * (OO * MODES) + (blk & 63) * MODES + (t - MODES)];
    __syncthreads();

    float acc = bre[0];
    const float wt = 6.2831853071795864769f * (float)t / 256.0f;
    #pragma unroll
    for (int k = 1; k < MODES; ++k) {
        float s, c;
        sincosf(wt * (float)k, &s, &c);
        acc += 2.0f * (bre[k] * c - bim[k] * s);
    }
    float v = acc * (1.0f / 16.0f);
    if (blk < BB * OO) v += mb[blk & 63];
    g[(size_t)blk * 256 + t] = v;
}

// ---------------------------------------------------------------------------
// K3: MFMA epilogue GEMM, ot-merged, pure bf16 single-term.
// out[b,o,h,w] = sum_c mw[o,c] x[b,c,h,w] + gx'[b,o,h] + gy[b,o,w]
// grid = B * 128 strips of 512 px; 4 waves; wave does 4 x 32-pixel tiles,
// computing ALL 64 o per tile (two 32x32 acc tiles share one x load/convert).
// NOTE: no min-waves clamp — round 3's (256,4) forced 64 VGPR and spilled.
__global__ void __launch_bounds__(256) k_final_mfma(
        const float* __restrict__ x,
        const float* __restrict__ mw,   // [O][C]
        const float* __restrict__ g,    // [2][B][O][256]
        float* __restrict__ out) {
    const int tid  = threadIdx.x;
    const int lane = tid & 63;
    const int wv   = tid >> 6;
    const int blk  = blockIdx.x;
    const int strip = blk & 127;
    const int b     = blk >> 7;
    const int nlo   = lane & 31;
    const int half  = lane >> 5;

    const float* gx = g + (size_t)(b * OO) * 256;
    const float* gy = g + (size_t)BB * OO * 256 + (size_t)(b * OO) * 256;

    // A fragments (weights) for both o-tiles, bf16, loaded once.
    short8v wf[2][4];
    #pragma unroll
    for (int ot = 0; ot < 2; ++ot) {
        const int o = ot * 32 + nlo;
        const float* wrow = mw + o * CC + 8 * half;
        #pragma unroll
        for (int kb = 0; kb < 4; ++kb) {
            int4v wi;
            #pragma unroll
            for (int p = 0; p < 4; ++p)
                wi[p] = (int)pack_bf16(wrow[kb * 16 + 2 * p], wrow[kb * 16 + 2 * p + 1]);
            wf[ot][kb] = __builtin_bit_cast(short8v, wi);
        }
    }

    const float* xb = x + (size_t)b * CC * (HH * WW);
    float*       ob = out + (size_t)b * OO * (HH * WW);

    for (int it = 0; it < 4; ++it) {
        const int p0 = strip * 512 + it * 128 + wv * 32;
        const int h  = p0 >> 8;
        const int w0 = p0 & 255;

        // gather B: x[c][p0+nlo], c = kb*16 + 8*half + i; convert per-kb so
        // only 8 floats are live at a time (register pressure control).
        short8v xh[4];
        #pragma unroll
        for (int kb = 0; kb < 4; ++kb) {
            float xv[8];
            #pragma unroll
            for (int i = 0; i < 8; ++i) {
                const int c = kb * 16 + 8 * half + i;
                xv[i] = xb[(size_t)c * (HH * WW) + p0 + nlo];
            }
            int4v xi;
            #pragma unroll
            for (int p = 0; p < 4; ++p)
                xi[p] = (int)pack_bf16(xv[2 * p], xv[2 * p + 1]);
            xh[kb] = __builtin_bit_cast(short8v, xi);
        }

        f32x16 acc0, acc1;
        #pragma unroll
        for (int i = 0; i < 16; ++i) { acc0[i] = 0.f; acc1[i] = 0.f; }

        #pragma unroll
        for (int kb = 0; kb < 4; ++kb) {
            acc0 = __builtin_amdgcn_mfma_f32_32x32x16_bf16(wf[0][kb], xh[kb], acc0, 0, 0, 0);
            acc1 = __builtin_amdgcn_mfma_f32_32x32x16_bf16(wf[1][kb], xh[kb], acc1, 0, 0, 0);
        }

        // epilogue: row(o_local) = (r&3) + 8*(r>>2) + 4*half, col = nlo
        #pragma unroll
        for (int r = 0; r < 16; ++r) {
            const int ol = (r & 3) + 8 * (r >> 2) + 4 * half;
            {
                const int o = ol;
                const float v = acc0[r] + gx[o * 256 + h] + gy[o * 256 + w0 + nlo];
                ob[(size_t)o * (HH * WW) + p0 + nlo] = v;
            }
            {
                const int o = 32 + ol;
                const float v = acc1[r] + gx[o * 256 + h] + gy[o * 256 + w0 + nlo];
                ob[(size_t)o * (HH * WW) + p0 + nlo] = v;
            }
        }
    }
}

// ---------------------------------------------------------------------------
extern "C" void kernel_launch(void* const* d_in, const int* in_sizes, int n_in,
                              void* d_out, int out_size, void* d_ws, size_t ws_size,
                              hipStream_t stream) {
    const float* x    = (const float*)d_in[0];
    const float* wxr  = (const float*)d_in[1];
    const float* wxi  = (const float*)d_in[2];
    const float* wyr  = (const float*)d_in[3];
    const float* wyi  = (const float*)d_in[4];
    const float* mixw = (const float*)d_in[5];
    const float* mixb = (const float*)d_in[6];
    float* out = (float*)d_out;
    float* ws  = (float*)d_ws;

    float* xbw   = ws + WS_XBAR;
    float* ftre  = ws + WS_FTRE;
    float* ftim  = ws + WS_FTIM;
    float* boxre = ws + WS_BOXRE;
    float* boxim = ws + WS_BOXIM;
    float* g     = ws + WS_G;
    float* partial = out;    // d_out as scratch: dead until k_final overwrites

    k_means<<<BB * CC * 4, 256, 0, stream>>>(x, xbw, partial);
    k_dft<<<2 * BB * CC, 256, 0, stream>>>(xbw, partial, ftre, ftim);
    k_modemix<<<2 * BB, 256, 0, stream>>>(ftre, ftim, wxr, wxi, wyr, wyi, boxre, boxim);
    k_synth<<<2 * BB * OO, 256, 0, stream>>>(boxre, boxim, mixb, g);
    k_final_mfma<<<BB * 128, 256, 0, stream>>>(x, mixw, g, out);
}

// Round 5
// 107.465 us; speedup vs baseline: 2.7662x; 1.9669x over previous
//
#include <hip/hip_runtime.h>
#include <cstddef>

// Problem constants
#define BB 8
#define CC 64
#define OO 64
#define HH 256
#define WW 256
#define MODES 16

// Workspace layout (float offsets)
#define WS_XBAR   0
#define WS_FTRE   262144
#define WS_FTIM   278528
#define WS_BOXRE  294912
#define WS_BOXIM  311296
#define WS_G      327680

typedef __attribute__((ext_vector_type(8)))  short short8v;
typedef __attribute__((ext_vector_type(4)))  int   int4v;
typedef __attribute__((ext_vector_type(16))) float f32x16;

// HW packed f32->bf16 (RNE): lo = bf16(a), hi = bf16(b)
__device__ __forceinline__ unsigned pack_bf16(float a, float b) {
    unsigned r;
    asm("v_cvt_pk_bf16_f32 %0, %1, %2" : "=v"(r) : "v"(a), "v"(b));
    return r;
}

// ---------------------------------------------------------------------------
// K1: grid = B*C*4. Block j of slice bc handles rows [j*64, j*64+64):
//  - row means -> xbw[bc][h] (final)
//  - column partial sums over its 64 rows -> partial[bc*4+j][w] (in d_out!)
__global__ void k_means(const float* __restrict__ x,
                        float* __restrict__ xbw,       // [B*C][256]
                        float* __restrict__ partial) { // [B*C*4][256] (d_out scratch)
    const int blk = blockIdx.x;                  // bc*4 + j
    const int bc  = blk >> 2;
    const int j   = blk & 3;
    const int t   = threadIdx.x;
    const int wave = t >> 6;
    const int lane = t & 63;
    const float* xs = x + (size_t)bc * (HH * WW);

    __shared__ float colsum[4][WW];

    float c0 = 0.f, c1 = 0.f, c2 = 0.f, c3 = 0.f;
    const int h0 = j * 64 + wave * 16;
    for (int r = 0; r < 16; ++r) {
        const int h = h0 + r;
        const float4 v = *reinterpret_cast<const float4*>(xs + (size_t)h * WW + lane * 4);
        c0 += v.x; c1 += v.y; c2 += v.z; c3 += v.w;
        float rs = (v.x + v.y) + (v.z + v.w);
        #pragma unroll
        for (int off = 32; off > 0; off >>= 1) rs += __shfl_xor(rs, off, 64);
        if (lane == 0) xbw[bc * HH + h] = rs * (1.0f / WW);
    }
    colsum[wave][lane * 4 + 0] = c0;
    colsum[wave][lane * 4 + 1] = c1;
    colsum[wave][lane * 4 + 2] = c2;
    colsum[wave][lane * 4 + 3] = c3;
    __syncthreads();
    partial[blk * WW + t] =
        (colsum[0][t] + colsum[1][t]) + (colsum[2][t] + colsum[3][t]);
}

// ---------------------------------------------------------------------------
// K2a: 16-mode ortho DFT. blk<512: row-mean vectors (xbw). blk>=512: column
// means assembled from the 4 partials (divide by H here).
__global__ void k_dft(const float* __restrict__ xbw,
                      const float* __restrict__ partial,
                      float* __restrict__ ftre,        // [1024][16]
                      float* __restrict__ ftim) {
    const int blk = blockIdx.x;
    const int t = threadIdx.x;
    __shared__ float vs[256];
    if (blk < 512) {
        vs[t] = xbw[(size_t)blk * 256 + t];
    } else {
        const int bc = blk - 512;
        vs[t] = ((partial[(bc * 4 + 0) * 256 + t] + partial[(bc * 4 + 1) * 256 + t]) +
                 (partial[(bc * 4 + 2) * 256 + t] + partial[(bc * 4 + 3) * 256 + t])) *
                (1.0f / HH);
    }
    __syncthreads();

    const int k = t >> 4;
    const int j = t & 15;
    float sre = 0.f, sim = 0.f;
    const float wk = 6.2831853071795864769f * (float)k / 256.0f;
    #pragma unroll
    for (int i = 0; i < 16; ++i) {
        const int h = j * 16 + i;
        float s, c;
        sincosf(wk * (float)h, &s, &c);
        sre += vs[h] * c;
        sim -= vs[h] * s;
    }
    #pragma unroll
    for (int m = 1; m < 16; m <<= 1) {
        sre += __shfl_xor(sre, m, 64);
        sim += __shfl_xor(sim, m, 64);
    }
    if (j == 0) {
        ftre[blk * MODES + k] = sre * (1.0f / 16.0f);
        ftim[blk * MODES + k] = sim * (1.0f / 16.0f);
    }
}

// ---------------------------------------------------------------------------
// K2b: channel mix in mode space.
__global__ void k_modemix(const float* __restrict__ ftre,
                          const float* __restrict__ ftim,
                          const float* __restrict__ wxr, const float* __restrict__ wxi,
                          const float* __restrict__ wyr, const float* __restrict__ wyi,
                          float* __restrict__ boxre, float* __restrict__ boxim) {
    const int blk = blockIdx.x;      // 0..15 : br = blk>>3, b = blk&7
    const int br  = blk >> 3;
    const int t   = threadIdx.x;

    const float* wr = br ? wyr : wxr;
    const float* wi = br ? wyi : wxi;

    __shared__ float fr[CC * MODES];
    __shared__ float fi[CC * MODES];
    #pragma unroll
    for (int i = 0; i < 4; ++i) {
        fr[t + i * 256] = ftre[blk * (CC * MODES) + t + i * 256];
        fi[t + i * 256] = ftim[blk * (CC * MODES) + t + i * 256];
    }
    __syncthreads();

    const int k  = t & 15;
    const int ob = t >> 4;
    #pragma unroll
    for (int p = 0; p < 4; ++p) {
        const int o = ob + p * 16;
        float are = 0.f, aim = 0.f;
        for (int c = 0; c < CC; ++c) {
            const float frv = fr[c * MODES + k];
            const float fiv = fi[c * MODES + k];
            const float wrv = wr[(c * OO + o) * MODES + k];
            const float wiv = wi[(c * OO + o) * MODES + k];
            are += frv * wrv - fiv * wiv;
            aim += frv * wiv + fiv * wrv;
        }
        boxre[blk * (OO * MODES) + o * MODES + k] = are;
        boxim[blk * (OO * MODES) + o * MODES + k] = aim;
    }
}

// ---------------------------------------------------------------------------
// K2c: inverse synthesis; mix_b folded into gx (br==0).
__global__ void k_synth(const float* __restrict__ boxre,
                        const float* __restrict__ boxim,
                        const float* __restrict__ mb,
                        float* __restrict__ g) {
    const int blk = blockIdx.x;      // (br*B+b)*64 + o
    const int t   = threadIdx.x;
    __shared__ float bre[MODES], bim[MODES];
    if (t < MODES)        bre[t] = boxre[(blk >> 6) * (OO * MODES) + (blk & 63) * MODES + t];
    else if (t < 2*MODES) bim[t - MODES] = boxim[(blk >> 6) * (OO * MODES) + (blk & 63) * MODES + (t - MODES)];
    __syncthreads();

    float acc = bre[0];
    const float wt = 6.2831853071795864769f * (float)t / 256.0f;
    #pragma unroll
    for (int k = 1; k < MODES; ++k) {
        float s, c;
        sincosf(wt * (float)k, &s, &c);
        acc += 2.0f * (bre[k] * c - bim[k] * s);
    }
    float v = acc * (1.0f / 16.0f);
    if (blk < BB * OO) v += mb[blk & 63];
    g[(size_t)blk * 256 + t] = v;
}

// ---------------------------------------------------------------------------
// K3: MFMA epilogue GEMM, ot-merged, pure bf16 single-term.
// out[b,o,h,w] = sum_c mw[o,c] x[b,c,h,w] + gx'[b,o,h] + gy[b,o,w]
// grid = B*256 (one h-row per block); 4 waves; wave wv handles pixels
// [wv*64, wv*64+64) as two 32-px tiles, computing ALL 64 o per tile.
// Critical for MLP: all 32 x-gather loads issued flat (xv[32]) before any
// cvt — round 4's per-kb scoping serialized them (149us); round 2's flat
// gather was 78us. No min-waves clamp (round 3: (256,4) -> 64 VGPR, spill).
__global__ void __launch_bounds__(256) k_final_mfma(
        const float* __restrict__ x,
        const float* __restrict__ mw,   // [O][C]
        const float* __restrict__ g,    // [2][B][O][256]
        float* __restrict__ out) {
    const int tid  = threadIdx.x;
    const int lane = tid & 63;
    const int wv   = tid >> 6;
    const int blk  = blockIdx.x;
    const int b    = blk >> 8;
    const int h    = blk & 255;
    const int nlo  = lane & 31;
    const int half = lane >> 5;

    const float* gx = g + (size_t)(b * OO) * 256;
    const float* gy = g + (size_t)BB * OO * 256 + (size_t)(b * OO) * 256;

    // gx[o,h] is block-uniform in h: hoist to LDS once.
    __shared__ float gxs[OO];
    if (tid < OO) gxs[tid] = gx[tid * 256 + h];

    // A fragments (weights) for both o-tiles, bf16, loaded once.
    short8v wf[2][4];
    #pragma unroll
    for (int ot = 0; ot < 2; ++ot) {
        const int o = ot * 32 + nlo;
        const float* wrow = mw + o * CC + 8 * half;
        #pragma unroll
        for (int kb = 0; kb < 4; ++kb) {
            int4v wi;
            #pragma unroll
            for (int p = 0; p < 4; ++p)
                wi[p] = (int)pack_bf16(wrow[kb * 16 + 2 * p], wrow[kb * 16 + 2 * p + 1]);
            wf[ot][kb] = __builtin_bit_cast(short8v, wi);
        }
    }
    __syncthreads();

    const float* xb = x + (size_t)b * CC * (HH * WW) + (size_t)h * WW;
    float*       ob = out + (size_t)b * OO * (HH * WW) + (size_t)h * WW;

    #pragma unroll
    for (int it = 0; it < 2; ++it) {
        const int w0 = wv * 64 + it * 32;

        // gather B: x[c][h][w0+nlo], c = kb*16 + 8*half + i — ALL 32 loads
        // issued before any use, so they overlap (32 in flight per lane).
        float xv[32];
        #pragma unroll
        for (int kb = 0; kb < 4; ++kb)
            #pragma unroll
            for (int i = 0; i < 8; ++i) {
                const int c = kb * 16 + 8 * half + i;
                xv[kb * 8 + i] = xb[(size_t)c * (HH * WW) + w0 + nlo];
            }

        short8v xh[4];
        #pragma unroll
        for (int kb = 0; kb < 4; ++kb) {
            int4v xi;
            #pragma unroll
            for (int p = 0; p < 4; ++p)
                xi[p] = (int)pack_bf16(xv[kb * 8 + 2 * p], xv[kb * 8 + 2 * p + 1]);
            xh[kb] = __builtin_bit_cast(short8v, xi);
        }

        f32x16 acc0, acc1;
        #pragma unroll
        for (int i = 0; i < 16; ++i) { acc0[i] = 0.f; acc1[i] = 0.f; }

        #pragma unroll
        for (int kb = 0; kb < 4; ++kb) {
            acc0 = __builtin_amdgcn_mfma_f32_32x32x16_bf16(wf[0][kb], xh[kb], acc0, 0, 0, 0);
            acc1 = __builtin_amdgcn_mfma_f32_32x32x16_bf16(wf[1][kb], xh[kb], acc1, 0, 0, 0);
        }

        // epilogue: row(o_local) = (r&3) + 8*(r>>2) + 4*half, col = nlo
        #pragma unroll
        for (int r = 0; r < 16; ++r) {
            const int ol = (r & 3) + 8 * (r >> 2) + 4 * half;
            {
                const int o = ol;
                const float v = acc0[r] + gxs[o] + gy[o * 256 + w0 + nlo];
                __builtin_nontemporal_store(v, &ob[(size_t)o * (HH * WW) + w0 + nlo]);
            }
            {
                const int o = 32 + ol;
                const float v = acc1[r] + gxs[o] + gy[o * 256 + w0 + nlo];
                __builtin_nontemporal_store(v, &ob[(size_t)o * (HH * WW) + w0 + nlo]);
            }
        }
    }
}

// ---------------------------------------------------------------------------
extern "C" void kernel_launch(void* const* d_in, const int* in_sizes, int n_in,
                              void* d_out, int out_size, void* d_ws, size_t ws_size,
                              hipStream_t stream) {
    const float* x    = (const float*)d_in[0];
    const float* wxr  = (const float*)d_in[1];
    const float* wxi  = (const float*)d_in[2];
    const float* wyr  = (const float*)d_in[3];
    const float* wyi  = (const float*)d_in[4];
    const float* mixw = (const float*)d_in[5];
    const float* mixb = (const float*)d_in[6];
    float* out = (float*)d_out;
    float* ws  = (float*)d_ws;

    float* xbw   = ws + WS_XBAR;
    float* ftre  = ws + WS_FTRE;
    float* ftim  = ws + WS_FTIM;
    float* boxre = ws + WS_BOXRE;
    float* boxim = ws + WS_BOXIM;
    float* g     = ws + WS_G;
    float* partial = out;    // d_out as scratch: dead until k_final overwrites

    k_means<<<BB * CC * 4, 256, 0, stream>>>(x, xbw, partial);
    k_dft<<<2 * BB * CC, 256, 0, stream>>>(xbw, partial, ftre, ftim);
    k_modemix<<<2 * BB, 256, 0, stream>>>(ftre, ftim, wxr, wxi, wyr, wyi, boxre, boxim);
    k_synth<<<2 * BB * OO, 256, 0, stream>>>(boxre, boxim, mixb, g);
    k_final_mfma<<<BB * 256, 256, 0, stream>>>(x, mixw, g, out);
}